// Round 1
// baseline (731.355 us; speedup 1.0000x reference)
//
#include <hip/hip_runtime.h>

// Problem constants (from reference)
#define NROWS   262144
#define IN_C    64
#define OUT_C   64
#define SLOTS   9

#define BLOCK      512                    // 8 waves
#define ROWS_PER_WAVE 16
#define TILE_ROWS  (8 * ROWS_PER_WAVE)    // 128 rows per block-tile
#define NTILES     (NROWS / TILE_ROWS)    // 2048
#define GRID       512                    // 2 blocks/CU, 4 tiles/block

typedef short short8 __attribute__((ext_vector_type(8)));
typedef float f32x4  __attribute__((ext_vector_type(4)));

struct XPtrs { const float* p[SLOTS]; };

// fp32 -> bf16 round-to-nearest-even (bit trick; NaN not a concern here)
__device__ __forceinline__ short bfr(float f) {
  unsigned u = __builtin_bit_cast(unsigned, f);
  u = u + 0x7FFFu + ((u >> 16) & 1u);
  return (short)(u >> 16);
}

__device__ __forceinline__ short8 pack8(float4 a, float4 b) {
  short8 r;
  r[0] = bfr(a.x); r[1] = bfr(a.y); r[2] = bfr(a.z); r[3] = bfr(a.w);
  r[4] = bfr(b.x); r[5] = bfr(b.y); r[6] = bfr(b.z); r[7] = bfr(b.w);
  return r;
}

// out[n,o] = sum_k sum_c x_k[n,c] * W[k,o,c] + sum_k bias[k,o]
// MFMA mfma_f32_16x16x32_bf16:
//   A[m = lane&15][k = (lane>>4)*8 + j]            (m = row)
//   B[k = (lane>>4)*8 + j][n = lane&15]            (n = o)
//   C/D: col = lane&15, row = (lane>>4)*4 + reg
__global__ __launch_bounds__(BLOCK, 4)
void scatter_vertical_kernel(XPtrs xs, const float* __restrict__ W,
                             const float* __restrict__ bias,
                             float* __restrict__ out) {
  // B fragments in exact MFMA order: [slot][h][ot][lane] -> short8
  // 9*2*4*64 * 16B = 73728 B; + bias => 2 blocks/CU on 160 KiB LDS.
  __shared__ short8 sB[SLOTS * 2 * 4 * 64];
  __shared__ float  sBias[OUT_C];

  const int tid = threadIdx.x;

  // ---- stage weights fp32->bf16 into B-fragment order (once per block) ----
  {
    const float4* W4 = (const float4*)W;
    unsigned short* sBu = (unsigned short*)sB;
    // 9*64*64 floats = 9216 float4 loads
    for (int i4 = tid; i4 < SLOTS * 64 * 16; i4 += BLOCK) {
      float4 w = W4[i4];
      int c    = (i4 & 15) << 2;        // 0..60, step 4
      int o    = (i4 >> 4) & 63;
      int slot = i4 >> 10;
      int h  = c >> 5;                  // which 32-col half (K-step parity)
      int q  = (c >> 3) & 3;            // quad owning these cols
      int j0 = c & 7;                   // 0 or 4 within the 8-elem fragment
      int l  = (q << 4) | (o & 15);     // lane = quad*16 + (o&15)
      int ot = o >> 4;
      int base = ((((slot * 2 + h) * 4 + ot) * 64 + l) << 3) + j0;
      sBu[base + 0] = (unsigned short)bfr(w.x);
      sBu[base + 1] = (unsigned short)bfr(w.y);
      sBu[base + 2] = (unsigned short)bfr(w.z);
      sBu[base + 3] = (unsigned short)bfr(w.w);
    }
    if (tid < OUT_C) {
      float s = 0.f;
      for (int k = 0; k < SLOTS; ++k) s += bias[k * OUT_C + tid];
      sBias[tid] = s;
    }
  }
  __syncthreads();

  const int wave = tid >> 6;
  const int lane = tid & 63;
  const int n16  = lane & 15;
  const int quad = lane >> 4;

  for (int tile = blockIdx.x; tile < NTILES; tile += gridDim.x) {
    const int row0 = tile * TILE_ROWS + wave * ROWS_PER_WAVE;

    f32x4 acc[4];
#pragma unroll
    for (int ot = 0; ot < 4; ++ot) acc[ot] = (f32x4){0.f, 0.f, 0.f, 0.f};

#pragma unroll
    for (int k = 0; k < SLOTS; ++k) {
      // A: lane supplies row (row0+n16), cols quad*8..+7 of each 32-col half
      const float* xr = xs.p[k] + (size_t)(row0 + n16) * IN_C + (quad << 3);
      float4 a_lo0 = *(const float4*)(xr + 0);
      float4 a_lo1 = *(const float4*)(xr + 4);
      float4 a_hi0 = *(const float4*)(xr + 32);
      float4 a_hi1 = *(const float4*)(xr + 36);
      short8 a0 = pack8(a_lo0, a_lo1);   // K-step h=0 (cols 0..31)
      short8 a1 = pack8(a_hi0, a_hi1);   // K-step h=1 (cols 32..63)

#pragma unroll
      for (int ot = 0; ot < 4; ++ot) {
        short8 b0 = sB[k * 512 + ot * 64 + lane];        // h=0
        short8 b1 = sB[k * 512 + 256 + ot * 64 + lane];  // h=1
        acc[ot] = __builtin_amdgcn_mfma_f32_16x16x32_bf16(a0, b0, acc[ot], 0, 0, 0);
        acc[ot] = __builtin_amdgcn_mfma_f32_16x16x32_bf16(a1, b1, acc[ot], 0, 0, 0);
      }
    }

    // ---- epilogue: bias add + store (C: col=lane&15, row=quad*4+reg) ----
#pragma unroll
    for (int ot = 0; ot < 4; ++ot) {
      const int o = ot * 16 + n16;
      const float bsum = sBias[o];
#pragma unroll
      for (int r = 0; r < 4; ++r) {
        const int row = row0 + quad * 4 + r;
        out[(size_t)row * OUT_C + o] = acc[ot][r] + bsum;
      }
    }
  }
}

extern "C" void kernel_launch(void* const* d_in, const int* in_sizes, int n_in,
                              void* d_out, int out_size, void* d_ws, size_t ws_size,
                              hipStream_t stream) {
  XPtrs xs;
  for (int i = 0; i < SLOTS; ++i) xs.p[i] = (const float*)d_in[i];
  const float* W    = (const float*)d_in[SLOTS];       // [9, 64, 64]
  const float* bias = (const float*)d_in[SLOTS + 1];   // [9, 64]
  float* out = (float*)d_out;                          // [N, 64] fp32

  hipLaunchKernelGGL(scatter_vertical_kernel, dim3(GRID), dim3(BLOCK), 0, stream,
                     xs, W, bias, out);
}

// Round 2
// 720.717 us; speedup vs baseline: 1.0148x; 1.0148x over previous
//
#include <hip/hip_runtime.h>

// Problem constants (from reference)
#define NROWS   262144
#define IN_C    64
#define OUT_C   64
#define SLOTS   9

#define BLOCK      512                    // 8 waves
#define ROWS_PER_WAVE 16
#define TILE_ROWS  (8 * ROWS_PER_WAVE)    // 128 rows per block-tile
#define NTILES     (NROWS / TILE_ROWS)    // 2048
#define GRID       512                    // 2 blocks/CU (LDS-capped), 4 tiles/block

typedef short short8 __attribute__((ext_vector_type(8)));
typedef float f32x4  __attribute__((ext_vector_type(4)));

struct XPtrs { const float* p[SLOTS]; };

// fp32 -> bf16 round-to-nearest-even (bit trick; NaN not a concern here)
__device__ __forceinline__ short bfr(float f) {
  unsigned u = __builtin_bit_cast(unsigned, f);
  u = u + 0x7FFFu + ((u >> 16) & 1u);
  return (short)(u >> 16);
}

__device__ __forceinline__ short8 pack8(float4 a, float4 b) {
  short8 r;
  r[0] = bfr(a.x); r[1] = bfr(a.y); r[2] = bfr(a.z); r[3] = bfr(a.w);
  r[4] = bfr(b.x); r[5] = bfr(b.y); r[6] = bfr(b.z); r[7] = bfr(b.w);
  return r;
}

// Issue all 4 A-loads for one slot (16 rows x 64 cols, this wave's stripe).
__device__ __forceinline__ void load_slot(const float* __restrict__ x,
                                          int row0, int n16, int quad,
                                          float4 v[4]) {
  const float* xr = x + (size_t)(row0 + n16) * IN_C + (quad << 3);
  v[0] = *(const float4*)(xr + 0);
  v[1] = *(const float4*)(xr + 4);
  v[2] = *(const float4*)(xr + 32);
  v[3] = *(const float4*)(xr + 36);
}

// out[n,o] = sum_k sum_c x_k[n,c] * W[k,o,c] + sum_k bias[k,o]
// MFMA mfma_f32_16x16x32_bf16:
//   A[m = lane&15][k = (lane>>4)*8 + j]            (m = row)
//   B[k = (lane>>4)*8 + j][n = lane&15]            (n = o)
//   C/D: col = lane&15, row = (lane>>4)*4 + reg
__global__ __launch_bounds__(BLOCK, 4)
void scatter_vertical_kernel(XPtrs xs, const float* __restrict__ W,
                             const float* __restrict__ bias,
                             float* __restrict__ out) {
  // B fragments in exact MFMA order: [slot][h][ot][lane] -> short8
  // 9*2*4*64 * 16B = 73728 B; 2 blocks/CU on 160 KiB LDS.
  __shared__ short8 sB[SLOTS * 2 * 4 * 64];
  __shared__ float  sBias[OUT_C];

  const int tid = threadIdx.x;

  // ---- stage weights fp32->bf16 into B-fragment order (once per block) ----
  {
    const float4* W4 = (const float4*)W;
    unsigned short* sBu = (unsigned short*)sB;
    for (int i4 = tid; i4 < SLOTS * 64 * 16; i4 += BLOCK) {
      float4 w = W4[i4];
      int c    = (i4 & 15) << 2;        // 0..60, step 4
      int o    = (i4 >> 4) & 63;
      int slot = i4 >> 10;
      int h  = c >> 5;                  // which 32-col half (K-step parity)
      int q  = (c >> 3) & 3;            // quad owning these cols
      int j0 = c & 7;                   // 0 or 4 within the 8-elem fragment
      int l  = (q << 4) | (o & 15);     // lane = quad*16 + (o&15)
      int ot = o >> 4;
      int base = ((((slot * 2 + h) * 4 + ot) * 64 + l) << 3) + j0;
      sBu[base + 0] = (unsigned short)bfr(w.x);
      sBu[base + 1] = (unsigned short)bfr(w.y);
      sBu[base + 2] = (unsigned short)bfr(w.z);
      sBu[base + 3] = (unsigned short)bfr(w.w);
    }
    if (tid < OUT_C) {
      float s = 0.f;
      for (int k = 0; k < SLOTS; ++k) s += bias[k * OUT_C + tid];
      sBias[tid] = s;
    }
  }
  __syncthreads();

  const int wave = tid >> 6;
  const int lane = tid & 63;
  const int n16  = lane & 15;
  const int quad = lane >> 4;

  for (int tile = blockIdx.x; tile < NTILES; tile += gridDim.x) {
    const int row0 = tile * TILE_ROWS + wave * ROWS_PER_WAVE;

    f32x4 acc[4];
#pragma unroll
    for (int ot = 0; ot < 4; ++ot) acc[ot] = (f32x4){0.f, 0.f, 0.f, 0.f};

    // ---- depth-2 software-pipelined K loop (9 slots, full unroll) ----
    float4 buf[3][4];                      // 3-deep register ring, 48 VGPR
    load_slot(xs.p[0], row0, n16, quad, buf[0]);
    load_slot(xs.p[1], row0, n16, quad, buf[1]);

#pragma unroll
    for (int k = 0; k < SLOTS; ++k) {
      if (k + 2 < SLOTS)
        load_slot(xs.p[k + 2], row0, n16, quad, buf[(k + 2) % 3]);

      float4* c = buf[k % 3];
      short8 a0 = pack8(c[0], c[1]);       // K-step h=0 (cols 0..31)
      short8 a1 = pack8(c[2], c[3]);       // K-step h=1 (cols 32..63)

#pragma unroll
      for (int ot = 0; ot < 4; ++ot) {
        short8 b0 = sB[k * 512 + ot * 64 + lane];        // h=0
        short8 b1 = sB[k * 512 + 256 + ot * 64 + lane];  // h=1
        acc[ot] = __builtin_amdgcn_mfma_f32_16x16x32_bf16(a0, b0, acc[ot], 0, 0, 0);
        acc[ot] = __builtin_amdgcn_mfma_f32_16x16x32_bf16(a1, b1, acc[ot], 0, 0, 0);
      }
    }

    // ---- epilogue: bias add + nontemporal store ----
    // C layout: col = lane&15 (o within 16-group), row = quad*4 + reg.
    // ot inner so the two 64B halves of each 128B out-line issue adjacently.
    float bsum[4];
#pragma unroll
    for (int ot = 0; ot < 4; ++ot) bsum[ot] = sBias[ot * 16 + n16];
#pragma unroll
    for (int r = 0; r < 4; ++r) {
      const size_t row = row0 + quad * 4 + r;
#pragma unroll
      for (int ot = 0; ot < 4; ++ot) {
        const int o = ot * 16 + n16;
        __builtin_nontemporal_store(acc[ot][r] + bsum[ot], &out[row * OUT_C + o]);
      }
    }
  }
}

extern "C" void kernel_launch(void* const* d_in, const int* in_sizes, int n_in,
                              void* d_out, int out_size, void* d_ws, size_t ws_size,
                              hipStream_t stream) {
  XPtrs xs;
  for (int i = 0; i < SLOTS; ++i) xs.p[i] = (const float*)d_in[i];
  const float* W    = (const float*)d_in[SLOTS];       // [9, 64, 64]
  const float* bias = (const float*)d_in[SLOTS + 1];   // [9, 64]
  float* out = (float*)d_out;                          // [N, 64] fp32

  hipLaunchKernelGGL(scatter_vertical_kernel, dim3(GRID), dim3(BLOCK), 0, stream,
                     xs, W, bias, out);
}